// Round 12
// baseline (466.182 us; speedup 1.0000x reference)
//
#include <hip/hip_runtime.h>
#include <hip/hip_bf16.h>

#define N_NODES 100000
#define N_EDGES 1600000
#define IN_DIM  128
#define HID     64
#define CAP_N   64         // padded per-NODE capacity (avg degree 16, P(deg>=64)~1e-18)
#define CNT_STRIDE 16      // one 4B counter per 64B line
#define PAIRS_LIM (N_EDGES - 1)

#define SC_EB   1024       // edges per scatter block (4/thread)
#define SC_BLOCKS ((N_EDGES + SC_EB - 1) / SC_EB)   // 1563
#define GEMM_BLOCKS ((N_NODES + 63) / 64)           // 1563
#define PREP_BLOCKS ((N_NODES + 255) / 256)         // 391
#define COPY_BLOCKS ((N_NODES + 15) / 16)           // 6250 (16 nodes/block, 1 group/node)

#define PITCH_IN  152      // bf16 units per LDS row for K=128 (gemm_in staging)
#define PITCH_HID 88       // bf16 units per LDS row for K=64  (agg staging)

typedef __attribute__((ext_vector_type(8))) short bf16x8;   // MFMA A/B frag (4 VGPRs)
typedef __attribute__((ext_vector_type(4))) float f32x4;    // MFMA C/D frag

__device__ inline unsigned short f2bf(float f) {
    __hip_bfloat16 b = __float2bfloat16(f);
    return *reinterpret_cast<unsigned short*>(&b);
}

// ---------------------------------------------------------------------------
// Pre-pack W matrices into B-fragment order bf16 + zero per-node counters.
// flat = (((kc*4 + nt)*4 + quad)*16 + n16)*8 + j ;  k = kc*32+quad*8+j, n = nt*16+n16
// ---------------------------------------------------------------------------
__global__ void wf_prep_kernel(const float* __restrict__ Wi,
                               const float* __restrict__ W1,
                               const float* __restrict__ W2,
                               const float* __restrict__ W3,
                               unsigned short* __restrict__ wf_in,
                               unsigned short* __restrict__ wf_hid,
                               int* __restrict__ cnt) {
    int t = blockIdx.x * 256 + threadIdx.x;
    if (t < N_NODES) cnt[(size_t)t * CNT_STRIDE] = 0;
    if (t < 8192) {  // Wi: K=128 -> kc in 0..3
        int j = t & 7, n16 = (t >> 3) & 15, quad = (t >> 7) & 3, nt = (t >> 9) & 3, kc = t >> 11;
        int k = kc * 32 + quad * 8 + j, n = nt * 16 + n16;
        wf_in[t] = f2bf(Wi[k * HID + n]);
    }
    if (t < 4096) {  // W1..W3: K=64 -> kc in 0..1
        int j = t & 7, n16 = (t >> 3) & 15, quad = (t >> 7) & 3, nt = (t >> 9) & 3, kc = t >> 11;
        int k = kc * 32 + quad * 8 + j, n = nt * 16 + n16;
        wf_hid[t]        = f2bf(W1[k * HID + n]);
        wf_hid[4096 + t] = f2bf(W2[k * HID + n]);
        wf_hid[8192 + t] = f2bf(W3[k * HID + n]);
    }
}

// ---------------------------------------------------------------------------
// FUSED prep (R8-verbatim): even blocks scatter edges into the PADDED
// per-node array (atomic/latency-bound); odd blocks run h0 = relu(x@Wi+bi)
// (MFMA/BW-bound). bid&1 interleave overlaps the two regimes per CU.
// ---------------------------------------------------------------------------
__global__ __launch_bounds__(256) void fused_scatter_gemm_kernel(
        const int* __restrict__ src,
        const int* __restrict__ tgt,
        const float* __restrict__ ea,
        int* __restrict__ cnt,
        int2* __restrict__ binned,
        const float* __restrict__ x,
        const unsigned short* __restrict__ wf,
        const float* __restrict__ bi,
        float* __restrict__ h0,
        __hip_bfloat16* __restrict__ hbf) {
    __shared__ unsigned short sX[64 * PITCH_IN];   // 19456 B (gemm branch only)
    const int tid = threadIdx.x;

    if ((blockIdx.x & 1) == 0) {
        // ================= scatter branch =================
        const int s  = blockIdx.x >> 1;
        const int e0 = s * SC_EB;
        #pragma unroll
        for (int k = 0; k < SC_EB / 256; ++k) {
            int e = e0 + tid + k * 256;
            if (e < N_EDGES) {
                int t = tgt[e];
                int r = atomicAdd(&cnt[(size_t)t * CNT_STRIDE], 1);
                if (r < CAP_N)   // overflow guard (P ~ 1e-13)
                    binned[(size_t)t * CAP_N + r] =
                        make_int2(src[e], __float_as_int(ea[e]));
            }
        }
        return;
    }

    // ================= gemm_in branch =================
    const int row0 = (blockIdx.x >> 1) * 64;

    #pragma unroll
    for (int it = 0; it < 8; ++it) {
        int i  = tid + it * 256;
        int r  = i >> 5;        // 32 float4 per row
        int kq = i & 31;
        int rg = row0 + r;
        float4 v = (rg < N_NODES)
                 ? ((const float4*)x)[(size_t)rg * (IN_DIM / 4) + kq]
                 : make_float4(0.f, 0.f, 0.f, 0.f);
        ushort4 pk;
        pk.x = f2bf(v.x); pk.y = f2bf(v.y); pk.z = f2bf(v.z); pk.w = f2bf(v.w);
        *(ushort4*)(sX + r * PITCH_IN + kq * 4) = pk;
    }
    __syncthreads();

    const int lane = tid & 63;
    const int wid  = tid >> 6;
    const int l16  = lane & 15;
    const int q    = lane >> 4;

    f32x4 acc[4] = {{0,0,0,0},{0,0,0,0},{0,0,0,0},{0,0,0,0}};
    const bf16x8* wf8 = (const bf16x8*)wf;

    #pragma unroll
    for (int kc = 0; kc < 4; ++kc) {
        bf16x8 af = *(const bf16x8*)(sX + (wid * 16 + l16) * PITCH_IN + kc * 32 + q * 8);
        #pragma unroll
        for (int nt = 0; nt < 4; ++nt) {
            bf16x8 bfr = wf8[((kc * 4 + nt) * 4 + q) * 16 + l16];
            acc[nt] = __builtin_amdgcn_mfma_f32_16x16x32_bf16(af, bfr, acc[nt], 0, 0, 0);
        }
    }

    // Epilogue: C/D layout col = lane&15, row = quad*4 + reg  [m89]
    #pragma unroll
    for (int nt = 0; nt < 4; ++nt) {
        float bb = bi[nt * 16 + l16];
        #pragma unroll
        for (int reg = 0; reg < 4; ++reg) {
            int rg = row0 + wid * 16 + q * 4 + reg;
            if (rg < N_NODES) {
                float v = fmaxf(acc[nt][reg] + bb, 0.0f);
                h0 [(size_t)rg * HID + nt * 16 + l16] = v;
                hbf[(size_t)rg * HID + nt * 16 + l16] = __float2bfloat16(v);
            }
        }
    }
}

// ---------------------------------------------------------------------------
// Bridge A: per-256-node block sums of clamped counts.
// ---------------------------------------------------------------------------
__global__ __launch_bounds__(256) void csr_partial_kernel(
        const int* __restrict__ cnt, int* __restrict__ bsum) {
    __shared__ int s[4];
    int t = blockIdx.x * 256 + threadIdx.x;
    int v = (t < N_NODES) ? min(cnt[(size_t)t * CNT_STRIDE], CAP_N) : 0;
    #pragma unroll
    for (int d = 1; d < 64; d <<= 1) v += __shfl_xor(v, d);
    if ((threadIdx.x & 63) == 0) s[threadIdx.x >> 6] = v;
    __syncthreads();
    if (threadIdx.x == 0) bsum[blockIdx.x] = s[0] + s[1] + s[2] + s[3];
}

// ---------------------------------------------------------------------------
// Bridge B: exclusive scan of the 391 block sums (one block).
// ---------------------------------------------------------------------------
__global__ void csr_scan_kernel(const int* __restrict__ bsum,
                                int* __restrict__ boffs) {
    __shared__ int s[512];
    const int tid = threadIdx.x;
    int v = (tid < PREP_BLOCKS) ? bsum[tid] : 0;
    s[tid] = v;
    __syncthreads();
    for (int off = 1; off < 512; off <<= 1) {
        int t = (tid >= off) ? s[tid - off] : 0;
        __syncthreads();
        s[tid] += t;
        __syncthreads();
    }
    if (tid < PREP_BLOCKS) boffs[tid] = s[tid] - v;
}

// ---------------------------------------------------------------------------
// Bridge C: per-node offsets (block scan + boffs). NO copy here.
// ---------------------------------------------------------------------------
__global__ __launch_bounds__(256) void csr_offsets_kernel(
        const int* __restrict__ cnt,
        const int* __restrict__ boffs,
        int* __restrict__ offs,
        int* __restrict__ counts) {
    __shared__ int wsum[4];
    const int b = blockIdx.x, tid = threadIdx.x;
    const int node = b * 256 + tid;
    int v = (node < N_NODES) ? min(cnt[(size_t)node * CNT_STRIDE], CAP_N) : 0;
    const int lane = tid & 63, wid = tid >> 6;
    int sc = v;
    #pragma unroll
    for (int d = 1; d < 64; d <<= 1) {
        int t = __shfl_up(sc, d);
        if (lane >= d) sc += t;
    }
    if (lane == 63) wsum[wid] = sc;
    __syncthreads();
    int wb = 0;
    for (int w = 0; w < wid; ++w) wb += wsum[w];
    if (node < N_NODES) {
        offs[node]   = boffs[b] + wb + sc - v;
        counts[node] = v;
    }
}

// ---------------------------------------------------------------------------
// Bridge D: copy valid pairs padded -> compact. ONE 16-lane group per NODE
// (100K independent groups; 1-2 coalesced 128B read+write iterations each).
// This is the kernel R9 got wrong (16 serial nodes/group at 391 blocks ->
// latency chain with no TLP).
// ---------------------------------------------------------------------------
__global__ __launch_bounds__(256) void csr_copy_kernel(
        const int* __restrict__ cnt,
        const int* __restrict__ offs,
        const int2* __restrict__ binned,
        int2* __restrict__ pairs) {
    const int tid  = threadIdx.x;
    const int g    = tid >> 4;          // group 0..15
    const int sub  = tid & 15;
    const int node = blockIdx.x * 16 + g;
    if (node >= N_NODES) return;
    const int c = min(cnt[(size_t)node * CNT_STRIDE], CAP_N);
    const int o = offs[node];
    const int2* sp = binned + (size_t)node * CAP_N;
    for (int i = sub; i < c; i += 16)
        pairs[o + i] = sp[i];
}

// ---------------------------------------------------------------------------
// FUSED: a = h + segment_sum(bf16(h)[src] * w) ; hnext = relu(a @ W + b).
// R4-verbatim pull-mode on the COMPACT CSR (65.5us measured in R4):
// rolling 1-deep wave-wide 64-pair prefetch (compact layout makes successive
// nodes' pair lines L1/L2-hot); 2 edges in flight per 16-lane group; 128B
// coalesced hbf row loads. cnt <= 64 so one chunk covers a node.
// ---------------------------------------------------------------------------
__global__ __launch_bounds__(256) void agg_gemm_kernel(
        const float* __restrict__ h,               // layer-l activations (f32)
        const __hip_bfloat16* __restrict__ hbf_in, // layer-l activations (bf16)
        const int* __restrict__ offs,
        const int* __restrict__ counts,
        const int2* __restrict__ pairs,
        const unsigned short* __restrict__ wf,     // fragment-order W (bf16 bits)
        const float* __restrict__ b,
        float* __restrict__ hnext,
        __hip_bfloat16* __restrict__ hbf_out,
        const int store_bf) {
    __shared__ unsigned short sXs[64 * PITCH_HID]; // 11264 B
    const int tid  = threadIdx.x;
    const int row0 = blockIdx.x * 64;
    const int lane = tid & 63;
    const int wid  = tid >> 6;
    const int grp  = lane >> 4;
    const int sub  = lane & 15;

    const int node0 = row0 + wid * 16;
    int beg_n = 0, cnt_n = 0;
    if (node0 < N_NODES) { beg_n = offs[node0]; cnt_n = counts[node0]; }
    int2 pl = pairs[min(beg_n + lane, PAIRS_LIM)];

    // ---- Phase 1: aggregate 16 nodes per wave into LDS (bf16) ----
    for (int t = 0; t < 16; ++t) {
        const int node = node0 + t;                // wave-uniform
        const int ccur = cnt_n;
        const int2 pl_cur = pl;
        if (t < 15) {                              // prefetch next node's pairs
            int nn = node + 1;
            if (nn < N_NODES) { beg_n = offs[nn]; cnt_n = counts[nn]; }
            else              { beg_n = 0;        cnt_n = 0; }
            pl = pairs[min(beg_n + lane, PAIRS_LIM)];
        }
        if (node < N_NODES) {
            float ax = 0.f, ay = 0.f, az = 0.f, aw = 0.f;
            const int last = ccur - 1;
            for (int i = 0; i < ccur; i += 8) {
                int e0 = i + grp;
                int e1 = i + 4 + grp;
                bool l0 = (e0 <= last);
                bool l1 = (e1 <= last);
                int s0  = __shfl(pl_cur.x, l0 ? e0 : last);
                int w0i = __shfl(pl_cur.y, l0 ? e0 : last);
                int s1  = __shfl(pl_cur.x, l1 ? e1 : last);
                int w1i = __shfl(pl_cur.y, l1 ? e1 : last);
                uint2 g0 = *(const uint2*)(hbf_in + (size_t)s0 * HID + sub * 4);
                uint2 g1 = *(const uint2*)(hbf_in + (size_t)s1 * HID + sub * 4);
                float w0 = l0 ? __int_as_float(w0i) : 0.0f;
                float w1 = l1 ? __int_as_float(w1i) : 0.0f;
                ax += w0 * __uint_as_float(g0.x << 16);
                ay += w0 * __uint_as_float(g0.x & 0xFFFF0000u);
                az += w0 * __uint_as_float(g0.y << 16);
                aw += w0 * __uint_as_float(g0.y & 0xFFFF0000u);
                ax += w1 * __uint_as_float(g1.x << 16);
                ay += w1 * __uint_as_float(g1.x & 0xFFFF0000u);
                az += w1 * __uint_as_float(g1.y << 16);
                aw += w1 * __uint_as_float(g1.y & 0xFFFF0000u);
            }
            ax += __shfl_xor(ax, 16); ay += __shfl_xor(ay, 16);
            az += __shfl_xor(az, 16); aw += __shfl_xor(aw, 16);
            ax += __shfl_xor(ax, 32); ay += __shfl_xor(ay, 32);
            az += __shfl_xor(az, 32); aw += __shfl_xor(aw, 32);
            if (grp == 0) {
                const float4 hv = *(const float4*)(h + (size_t)node * HID + sub * 4);
                ushort4 pk;
                pk.x = f2bf(hv.x + ax); pk.y = f2bf(hv.y + ay);
                pk.z = f2bf(hv.z + az); pk.w = f2bf(hv.w + aw);
                *(ushort4*)(sXs + (wid * 16 + t) * PITCH_HID + sub * 4) = pk;
            }
        } else if (grp == 0) {
            ushort4 z; z.x = 0; z.y = 0; z.z = 0; z.w = 0;
            *(ushort4*)(sXs + (wid * 16 + t) * PITCH_HID + sub * 4) = z;
        }
    }
    __syncthreads();

    // ---- Phase 2: 16x16x32 bf16 MFMA (K=64) + relu epilogue ----
    const int l16 = lane & 15;
    const int q   = lane >> 4;

    f32x4 acc[4] = {{0,0,0,0},{0,0,0,0},{0,0,0,0},{0,0,0,0}};
    const bf16x8* wf8 = (const bf16x8*)wf;

    #pragma unroll
    for (int kc = 0; kc < 2; ++kc) {
        bf16x8 af = *(const bf16x8*)(sXs + (wid * 16 + l16) * PITCH_HID + kc * 32 + q * 8);
        #pragma unroll
        for (int nt = 0; nt < 4; ++nt) {
            bf16x8 bfr = wf8[((kc * 4 + nt) * 4 + q) * 16 + l16];
            acc[nt] = __builtin_amdgcn_mfma_f32_16x16x32_bf16(af, bfr, acc[nt], 0, 0, 0);
        }
    }

    #pragma unroll
    for (int nt = 0; nt < 4; ++nt) {
        float bb = b[nt * 16 + l16];
        #pragma unroll
        for (int reg = 0; reg < 4; ++reg) {
            int rg = row0 + wid * 16 + q * 4 + reg;
            if (rg < N_NODES) {
                float v = fmaxf(acc[nt][reg] + bb, 0.0f);
                hnext[(size_t)rg * HID + nt * 16 + l16] = v;
                if (store_bf)
                    hbf_out[(size_t)rg * HID + nt * 16 + l16] = __float2bfloat16(v);
            }
        }
    }
}

extern "C" void kernel_launch(void* const* d_in, const int* in_sizes, int n_in,
                              void* d_out, int out_size, void* d_ws, size_t ws_size,
                              hipStream_t stream) {
    const float* x   = (const float*)d_in[0];
    const int*   ei  = (const int*)  d_in[1];   // (2, E): [src | tgt]
    const float* ea  = (const float*)d_in[2];
    const float* Wi  = (const float*)d_in[3];
    const float* bi  = (const float*)d_in[4];
    const float* W1  = (const float*)d_in[5];
    const float* b1  = (const float*)d_in[6];
    const float* W2  = (const float*)d_in[7];
    const float* b2  = (const float*)d_in[8];
    const float* W3  = (const float*)d_in[9];
    const float* b3  = (const float*)d_in[10];
    const float* bl[3] = { b1, b2, b3 };
    float* out = (float*)d_out;  // (4, N, HID)

    const int* src = ei;
    const int* tgt = ei + N_EDGES;

    // Workspace layout.
    int2* binned = (int2*)d_ws;                                      // N*CAP_N*8B = 51.2 MB
    int* cnt = (int*)(binned + (size_t)N_NODES * CAP_N);             // N*16 ints (6.4 MB)
    int2* pairs = (int2*)(cnt + (size_t)N_NODES * CNT_STRIDE);       // E*8B = 12.8 MB
    int* offs   = (int*)(pairs + N_EDGES);                           // N ints
    int* counts = offs + N_NODES;                                    // N ints
    int* bsum   = counts + N_NODES;                                  // 391 ints
    int* boffs  = bsum + PREP_BLOCKS;                                // 391 ints
    __hip_bfloat16* hbf0 = (__hip_bfloat16*)(boffs + PREP_BLOCKS + 2);
    __hip_bfloat16* hbf1 = hbf0 + (size_t)N_NODES * HID;             // N*HID bf16
    unsigned short* wf_in  = (unsigned short*)(hbf1 + (size_t)N_NODES * HID);
    unsigned short* wf_hid = wf_in + 8192;                           // 3 x 4096

    wf_prep_kernel<<<PREP_BLOCKS, 256, 0, stream>>>(Wi, W1, W2, W3,
                                                    wf_in, wf_hid, cnt);

    fused_scatter_gemm_kernel<<<SC_BLOCKS + GEMM_BLOCKS, 256, 0, stream>>>(
        src, tgt, ea, cnt, binned, x, wf_in, bi, out, hbf0);

    csr_partial_kernel<<<PREP_BLOCKS, 256, 0, stream>>>(cnt, bsum);
    csr_scan_kernel   <<<1, 512, 0, stream>>>(bsum, boffs);
    csr_offsets_kernel<<<PREP_BLOCKS, 256, 0, stream>>>(cnt, boffs, offs, counts);
    csr_copy_kernel   <<<COPY_BLOCKS, 256, 0, stream>>>(cnt, offs, binned, pairs);

    __hip_bfloat16* hin  = hbf0;
    __hip_bfloat16* hout = hbf1;
    for (int l = 0; l < 3; ++l) {
        const float* hl = out + (size_t)l * N_NODES * HID;
        float* hn       = out + (size_t)(l + 1) * N_NODES * HID;
        agg_gemm_kernel<<<GEMM_BLOCKS, 256, 0, stream>>>(
            hl, hin, offs, counts, pairs,
            wf_hid + (size_t)l * 4096, bl[l], hn, hout, (l < 2) ? 1 : 0);
        __hip_bfloat16* t = hin; hin = hout; hout = t;
    }
}

// Round 13
// 380.278 us; speedup vs baseline: 1.2259x; 1.2259x over previous
//
#include <hip/hip_runtime.h>
#include <hip/hip_bf16.h>

#define N_NODES 100000
#define N_EDGES 1600000
#define IN_DIM  128
#define HID     64
#define BIN_NODES 256
#define NBINS   ((N_NODES + BIN_NODES - 1) / BIN_NODES)   // 391 bins of 256 nodes
#define EB      2048       // edges per scatter block
#define CAP     8192       // padded per-BIN capacity (avg fill 4096, sd~64)
#define CAP_N   64         // padded per-NODE capacity (avg degree 16)

#define SC_BLOCKS ((N_EDGES + EB - 1) / EB)         // 782
#define GEMM_BLOCKS ((N_NODES + 63) / 64)           // 1563
#define PREP_BLOCKS ((N_NODES + 255) / 256)         // 391

#define PITCH_IN  152      // bf16 units per LDS row for K=128 (gemm_in staging)
#define PITCH_HID 88       // bf16 units per LDS row for K=64  (agg staging)

typedef __attribute__((ext_vector_type(8))) short bf16x8;   // MFMA A/B frag (4 VGPRs)
typedef __attribute__((ext_vector_type(4))) float f32x4;    // MFMA C/D frag

__device__ inline unsigned short f2bf(float f) {
    __hip_bfloat16 b = __float2bfloat16(f);
    return *reinterpret_cast<unsigned short*>(&b);
}

// ---------------------------------------------------------------------------
// Pre-pack W matrices into B-fragment order bf16 + init padded-bin cursors.
// flat = (((kc*4 + nt)*4 + quad)*16 + n16)*8 + j ;  k = kc*32+quad*8+j, n = nt*16+n16
// ---------------------------------------------------------------------------
__global__ void wf_prep_kernel(const float* __restrict__ Wi,
                               const float* __restrict__ W1,
                               const float* __restrict__ W2,
                               const float* __restrict__ W3,
                               unsigned short* __restrict__ wf_in,
                               unsigned short* __restrict__ wf_hid,
                               int* __restrict__ g_bin_cursor) {
    int t = blockIdx.x * 256 + threadIdx.x;
    if (t < NBINS) g_bin_cursor[t] = t * CAP;
    if (t < 8192) {  // Wi: K=128 -> kc in 0..3
        int j = t & 7, n16 = (t >> 3) & 15, quad = (t >> 7) & 3, nt = (t >> 9) & 3, kc = t >> 11;
        int k = kc * 32 + quad * 8 + j, n = nt * 16 + n16;
        wf_in[t] = f2bf(Wi[k * HID + n]);
    }
    if (t < 4096) {  // W1..W3: K=64 -> kc in 0..1
        int j = t & 7, n16 = (t >> 3) & 15, quad = (t >> 7) & 3, nt = (t >> 9) & 3, kc = t >> 11;
        int k = kc * 32 + quad * 8 + j, n = nt * 16 + n16;
        wf_hid[t]        = f2bf(W1[k * HID + n]);
        wf_hid[4096 + t] = f2bf(W2[k * HID + n]);
        wf_hid[8192 + t] = f2bf(W3[k * HID + n]);
    }
}

// ---------------------------------------------------------------------------
// FUSED prep: R4's proven LDS-sorted bin scatter (block-local sort -> ONE
// global atomic per touched bin -> semi-coalesced output; ~30us standalone)
// interleaved 1:2 with gemm_in blocks (h0 = relu(x@Wi+bi)) so the MFMA/BW
// work hides in the scatter's latency slack (R8-proven).
// Record: high32 = w bits, low32 = (local_tgt<<17) | src (local_tgt 8 bits).
// ---------------------------------------------------------------------------
struct ScatterS {
    unsigned long long srec[EB];   // 16384 B (8B-aligned first)
    unsigned short sbin[EB];       //  4096 B
    int cnt[NBINS];
    int lstart[NBINS];
    int lbase[NBINS];
    int stot;
};
struct GemmS {
    unsigned short sX[64 * PITCH_IN];   // 19456 B
};
#define FUSED_SMEM ((sizeof(ScatterS) > sizeof(GemmS)) ? sizeof(ScatterS) : sizeof(GemmS))

__global__ __launch_bounds__(256) void fused_scatter_gemm_kernel(
        const int* __restrict__ src,
        const int* __restrict__ tgt,
        const float* __restrict__ ea,
        int* __restrict__ g_bin_cursor,
        unsigned long long* __restrict__ binned,
        const float* __restrict__ x,
        const unsigned short* __restrict__ wf,
        const float* __restrict__ bi,
        float* __restrict__ h0,
        __hip_bfloat16* __restrict__ hbf) {
    __shared__ __align__(16) unsigned char smem[FUSED_SMEM];
    const int tid = threadIdx.x;

    // Block mapping: bid < 2*SC -> even=scatter, odd=gemm; tail -> gemm.
    int sb = -1, gb = -1;
    if (blockIdx.x < 2 * SC_BLOCKS) {
        if ((blockIdx.x & 1) == 0) sb = blockIdx.x >> 1;
        else                       gb = blockIdx.x >> 1;
    } else {
        gb = SC_BLOCKS + (blockIdx.x - 2 * SC_BLOCKS);
    }

    if (sb >= 0) {
        // ================= scatter branch (R4 verbatim) =================
        ScatterS* S = reinterpret_cast<ScatterS*>(smem);
        for (int i = tid; i < NBINS; i += 256) S->cnt[i] = 0;
        __syncthreads();

        const int e0 = sb * EB;
        int myb[EB / 256];
        unsigned long long myrec[EB / 256];
        #pragma unroll
        for (int i = 0; i < EB / 256; ++i) {
            int e = e0 + tid + i * 256;
            if (e < N_EDGES) {
                int t = tgt[e];
                int b = t >> 8;
                myb[i] = b;
                myrec[i] = ((unsigned long long)(unsigned)__float_as_int(ea[e]) << 32)
                         | ((unsigned)(t & 255) << 17) | (unsigned)src[e];
                atomicAdd(&S->cnt[b], 1);
            } else {
                myb[i] = -1;
            }
        }
        __syncthreads();

        // Wave 0: ripple exclusive scan of cnt[0..NBINS) -> lstart
        if (tid < 64) {
            int carry = 0;
            for (int c = 0; c < (NBINS + 63) / 64; ++c) {
                int idx = c * 64 + tid;
                int v = (idx < NBINS) ? S->cnt[idx] : 0;
                int sc = v;
                #pragma unroll
                for (int d = 1; d < 64; d <<= 1) {
                    int t2 = __shfl_up(sc, d);
                    if (tid >= d) sc += t2;
                }
                if (idx < NBINS) S->lstart[idx] = carry + sc - v;
                carry += __shfl(sc, 63);
            }
            if (tid == 0) S->stot = carry;
        }
        __syncthreads();

        // One global atomic per touched bin for this block's base.
        for (int i = tid; i < NBINS; i += 256)
            if (S->cnt[i]) S->lbase[i] = atomicAdd(&g_bin_cursor[i], S->cnt[i]);
        __syncthreads();
        for (int i = tid; i < NBINS; i += 256) S->cnt[i] = 0;   // reuse as cursor
        __syncthreads();

        // Local scatter into bin-sorted LDS order.
        #pragma unroll
        for (int i = 0; i < EB / 256; ++i) {
            if (myb[i] >= 0) {
                int r = atomicAdd(&S->cnt[myb[i]], 1);
                int p = S->lstart[myb[i]] + r;
                S->srec[p] = myrec[i];
                S->sbin[p] = (unsigned short)myb[i];
            }
        }
        __syncthreads();

        // Output in sorted order -> per-bin contiguous runs.
        const int tot = S->stot;
        for (int i = tid; i < tot; i += 256) {
            int b = S->sbin[i];
            binned[(size_t)S->lbase[b] + (i - S->lstart[b])] = S->srec[i];
        }
        return;
    }

    // ================= gemm_in branch =================
    GemmS* G = reinterpret_cast<GemmS*>(smem);
    const int row0 = gb * 64;

    #pragma unroll
    for (int it = 0; it < 8; ++it) {
        int i  = tid + it * 256;
        int r  = i >> 5;        // 32 float4 per row
        int kq = i & 31;
        int rg = row0 + r;
        float4 v = (rg < N_NODES)
                 ? ((const float4*)x)[(size_t)rg * (IN_DIM / 4) + kq]
                 : make_float4(0.f, 0.f, 0.f, 0.f);
        ushort4 pk;
        pk.x = f2bf(v.x); pk.y = f2bf(v.y); pk.z = f2bf(v.z); pk.w = f2bf(v.w);
        *(ushort4*)(G->sX + r * PITCH_IN + kq * 4) = pk;
    }
    __syncthreads();

    const int lane = tid & 63;
    const int wid  = tid >> 6;
    const int l16  = lane & 15;
    const int q    = lane >> 4;

    f32x4 acc[4] = {{0,0,0,0},{0,0,0,0},{0,0,0,0},{0,0,0,0}};
    const bf16x8* wf8 = (const bf16x8*)wf;

    #pragma unroll
    for (int kc = 0; kc < 4; ++kc) {
        bf16x8 af = *(const bf16x8*)(G->sX + (wid * 16 + l16) * PITCH_IN + kc * 32 + q * 8);
        #pragma unroll
        for (int nt = 0; nt < 4; ++nt) {
            bf16x8 bfr = wf8[((kc * 4 + nt) * 4 + q) * 16 + l16];
            acc[nt] = __builtin_amdgcn_mfma_f32_16x16x32_bf16(af, bfr, acc[nt], 0, 0, 0);
        }
    }

    // Epilogue: C/D layout col = lane&15, row = quad*4 + reg  [m89]
    #pragma unroll
    for (int nt = 0; nt < 4; ++nt) {
        float bb = bi[nt * 16 + l16];
        #pragma unroll
        for (int reg = 0; reg < 4; ++reg) {
            int rg = row0 + wid * 16 + q * 4 + reg;
            if (rg < N_NODES) {
                float v = fmaxf(acc[nt][reg] + bb, 0.0f);
                h0 [(size_t)rg * HID + nt * 16 + l16] = v;
                hbf[(size_t)rg * HID + nt * 16 + l16] = __float2bfloat16(v);
            }
        }
    }
}

// ---------------------------------------------------------------------------
// fine_fill (padded output): one pass per bin. LDS per-node cursors; each
// record goes to pairs[node*CAP_N + r]; cnt2[node] written at the end.
// Half the work of R4's fine_fill (no histogram/scan pass, single binned read).
// ---------------------------------------------------------------------------
__global__ __launch_bounds__(1024) void fine_fill_kernel(
        const unsigned long long* __restrict__ binned,
        const int* __restrict__ g_bin_cursor,
        int* __restrict__ cnt2,
        int2* __restrict__ pairs) {
    __shared__ int ncur[256];
    const int b   = blockIdx.x;
    const int tid = threadIdx.x;
    const int ebeg = b * CAP;
    const int ecnt = g_bin_cursor[b] - ebeg;

    if (tid < 256) ncur[tid] = 0;
    __syncthreads();
    for (int i = tid; i < ecnt; i += 1024) {
        unsigned long long rec = binned[ebeg + i];
        int lt = (int)((rec >> 17) & 255);
        int r  = atomicAdd(&ncur[lt], 1);
        if (r < CAP_N)   // overflow guard (P(deg>=64) ~ 1e-18 per node)
            pairs[(size_t)(b * 256 + lt) * CAP_N + r] =
                make_int2((int)(rec & 0x1FFFF), (int)(rec >> 32));
    }
    __syncthreads();
    if (tid < 256) {
        int node = b * 256 + tid;
        if (node < N_NODES) cnt2[node] = min(ncur[tid], CAP_N);
    }
}

// ---------------------------------------------------------------------------
// FUSED: a = h + segment_sum(bf16(h)[src] * w) ; hnext = relu(a @ W + b).
// R8-VERBATIM agg (the ~46us form, fastest measured): counts preloaded via
// lanes 0-15 + shfl; rolling 1-deep wave-wide pair prefetch clamped to
// min(lane, cnt-1); 2 edges in flight per 16-lane group; 128B coalesced
// hbf row loads. Only change: cnt2 is compact (coalesced 16-lane read).
// ---------------------------------------------------------------------------
__global__ __launch_bounds__(256) void agg_gemm_kernel(
        const float* __restrict__ h,               // layer-l activations (f32)
        const __hip_bfloat16* __restrict__ hbf_in, // layer-l activations (bf16)
        const int* __restrict__ cnt2,
        const int2* __restrict__ pairs,            // padded per-node [N][CAP_N]
        const unsigned short* __restrict__ wf,     // fragment-order W (bf16 bits)
        const float* __restrict__ b,
        float* __restrict__ hnext,
        __hip_bfloat16* __restrict__ hbf_out,
        const int store_bf) {
    __shared__ unsigned short sXs[64 * PITCH_HID]; // 11264 B
    const int tid  = threadIdx.x;
    const int row0 = blockIdx.x * 64;
    const int lane = tid & 63;
    const int wid  = tid >> 6;
    const int grp  = lane >> 4;
    const int sub  = lane & 15;

    const int node0 = row0 + wid * 16;

    // Counts for this wave's 16 nodes: lanes 0-15 load (coalesced), shfl-bcast.
    int cv = 0;
    {
        int nl = node0 + (lane & 15);
        if (lane < 16 && nl < N_NODES) cv = cnt2[nl];   // already clamped <= 64
    }

    // Prefetch node0's pair block (clamped: only lines covering [0,cnt) fetched).
    int c0 = __shfl(cv, 0);
    int2 pl = pairs[(size_t)min(node0, N_NODES - 1) * CAP_N + min(lane, max(c0 - 1, 0))];

    // ---- Phase 1: aggregate 16 nodes per wave into LDS (bf16) ----
    for (int t = 0; t < 16; ++t) {
        const int node = node0 + t;                // wave-uniform
        const int ccur = __shfl(cv, t);
        const int2 pl_cur = pl;
        if (t < 15) {                              // prefetch next node's pairs
            int cn = __shfl(cv, t + 1);
            pl = pairs[(size_t)min(node + 1, N_NODES - 1) * CAP_N
                        + min(lane, max(cn - 1, 0))];
        }
        if (node < N_NODES) {
            float ax = 0.f, ay = 0.f, az = 0.f, aw = 0.f;
            const int last = ccur - 1;
            for (int i = 0; i < ccur; i += 8) {
                int e0 = i + grp;
                int e1 = i + 4 + grp;
                bool l0 = (e0 <= last);
                bool l1 = (e1 <= last);
                int s0  = __shfl(pl_cur.x, l0 ? e0 : last);
                int w0i = __shfl(pl_cur.y, l0 ? e0 : last);
                int s1  = __shfl(pl_cur.x, l1 ? e1 : last);
                int w1i = __shfl(pl_cur.y, l1 ? e1 : last);
                uint2 g0 = *(const uint2*)(hbf_in + (size_t)s0 * HID + sub * 4);
                uint2 g1 = *(const uint2*)(hbf_in + (size_t)s1 * HID + sub * 4);
                float w0 = l0 ? __int_as_float(w0i) : 0.0f;
                float w1 = l1 ? __int_as_float(w1i) : 0.0f;
                ax += w0 * __uint_as_float(g0.x << 16);
                ay += w0 * __uint_as_float(g0.x & 0xFFFF0000u);
                az += w0 * __uint_as_float(g0.y << 16);
                aw += w0 * __uint_as_float(g0.y & 0xFFFF0000u);
                ax += w1 * __uint_as_float(g1.x << 16);
                ay += w1 * __uint_as_float(g1.x & 0xFFFF0000u);
                az += w1 * __uint_as_float(g1.y << 16);
                aw += w1 * __uint_as_float(g1.y & 0xFFFF0000u);
            }
            ax += __shfl_xor(ax, 16); ay += __shfl_xor(ay, 16);
            az += __shfl_xor(az, 16); aw += __shfl_xor(aw, 16);
            ax += __shfl_xor(ax, 32); ay += __shfl_xor(ay, 32);
            az += __shfl_xor(az, 32); aw += __shfl_xor(aw, 32);
            if (grp == 0) {
                const float4 hv = *(const float4*)(h + (size_t)node * HID + sub * 4);
                ushort4 pk;
                pk.x = f2bf(hv.x + ax); pk.y = f2bf(hv.y + ay);
                pk.z = f2bf(hv.z + az); pk.w = f2bf(hv.w + aw);
                *(ushort4*)(sXs + (wid * 16 + t) * PITCH_HID + sub * 4) = pk;
            }
        } else if (grp == 0) {
            ushort4 z; z.x = 0; z.y = 0; z.z = 0; z.w = 0;
            *(ushort4*)(sXs + (wid * 16 + t) * PITCH_HID + sub * 4) = z;
        }
    }
    __syncthreads();

    // ---- Phase 2: 16x16x32 bf16 MFMA (K=64) + relu epilogue ----
    const int l16 = lane & 15;
    const int q   = lane >> 4;

    f32x4 acc[4] = {{0,0,0,0},{0,0,0,0},{0,0,0,0},{0,0,0,0}};
    const bf16x8* wf8 = (const bf16x8*)wf;

    #pragma unroll
    for (int kc = 0; kc < 2; ++kc) {
        bf16x8 af = *(const bf16x8*)(sXs + (wid * 16 + l16) * PITCH_HID + kc * 32 + q * 8);
        #pragma unroll
        for (int nt = 0; nt < 4; ++nt) {
            bf16x8 bfr = wf8[((kc * 4 + nt) * 4 + q) * 16 + l16];
            acc[nt] = __builtin_amdgcn_mfma_f32_16x16x32_bf16(af, bfr, acc[nt], 0, 0, 0);
        }
    }

    #pragma unroll
    for (int nt = 0; nt < 4; ++nt) {
        float bb = b[nt * 16 + l16];
        #pragma unroll
        for (int reg = 0; reg < 4; ++reg) {
            int rg = row0 + wid * 16 + q * 4 + reg;
            if (rg < N_NODES) {
                float v = fmaxf(acc[nt][reg] + bb, 0.0f);
                hnext[(size_t)rg * HID + nt * 16 + l16] = v;
                if (store_bf)
                    hbf_out[(size_t)rg * HID + nt * 16 + l16] = __float2bfloat16(v);
            }
        }
    }
}

extern "C" void kernel_launch(void* const* d_in, const int* in_sizes, int n_in,
                              void* d_out, int out_size, void* d_ws, size_t ws_size,
                              hipStream_t stream) {
    const float* x   = (const float*)d_in[0];
    const int*   ei  = (const int*)  d_in[1];   // (2, E): [src | tgt]
    const float* ea  = (const float*)d_in[2];
    const float* Wi  = (const float*)d_in[3];
    const float* bi  = (const float*)d_in[4];
    const float* W1  = (const float*)d_in[5];
    const float* b1  = (const float*)d_in[6];
    const float* W2  = (const float*)d_in[7];
    const float* b2  = (const float*)d_in[8];
    const float* W3  = (const float*)d_in[9];
    const float* b3  = (const float*)d_in[10];
    const float* bl[3] = { b1, b2, b3 };
    float* out = (float*)d_out;  // (4, N, HID)

    const int* src = ei;
    const int* tgt = ei + N_EDGES;

    // Workspace layout.
    unsigned long long* binned = (unsigned long long*)d_ws;          // NBINS*CAP*8B = 25.6 MB
    int2* pairs = (int2*)(binned + (size_t)NBINS * CAP);             // N*CAP_N*8B = 51.2 MB
    int* cnt2   = (int*)(pairs + (size_t)N_NODES * CAP_N);           // N ints
    int* g_bin_cursor = cnt2 + N_NODES;                              // NBINS ints
    __hip_bfloat16* hbf0 = (__hip_bfloat16*)(g_bin_cursor + NBINS + 1);
    __hip_bfloat16* hbf1 = hbf0 + (size_t)N_NODES * HID;             // N*HID bf16
    unsigned short* wf_in  = (unsigned short*)(hbf1 + (size_t)N_NODES * HID);
    unsigned short* wf_hid = wf_in + 8192;                           // 3 x 4096

    wf_prep_kernel<<<PREP_BLOCKS, 256, 0, stream>>>(Wi, W1, W2, W3,
                                                    wf_in, wf_hid, g_bin_cursor);

    const int fused_grid = 2 * SC_BLOCKS + (GEMM_BLOCKS - SC_BLOCKS);  // 2345
    fused_scatter_gemm_kernel<<<fused_grid, 256, 0, stream>>>(
        src, tgt, ea, g_bin_cursor, binned, x, wf_in, bi, out, hbf0);

    fine_fill_kernel<<<NBINS, 1024, 0, stream>>>(binned, g_bin_cursor,
                                                 cnt2, pairs);

    __hip_bfloat16* hin  = hbf0;
    __hip_bfloat16* hout = hbf1;
    for (int l = 0; l < 3; ++l) {
        const float* hl = out + (size_t)l * N_NODES * HID;
        float* hn       = out + (size_t)(l + 1) * N_NODES * HID;
        agg_gemm_kernel<<<GEMM_BLOCKS, 256, 0, stream>>>(
            hl, hin, cnt2, pairs,
            wf_hid + (size_t)l * 4096, bl[l], hn, hout, (l < 2) ? 1 : 0);
        __hip_bfloat16* t = hin; hin = hout; hout = t;
    }
}